// Round 2
// 456.731 us; speedup vs baseline: 1.0026x; 1.0026x over previous
//
#include <hip/hip_runtime.h>
#include <stdint.h>

// BiRealConv2d: y = conv2d(sign(x), scale[o]*sign(w)), NCHW, 3x3, pad 1.
// Exact integer XNOR-popcount formulation.
// v2 (resubmit; round-1 bench was an infra failure, no kernel verdict):
//     conv restructured tap-outer with pc[32] accumulators (forces x-words and
//     accumulators resident in VGPRs; round-0 build showed VGPR_Count=32 ->
//     x reloaded from L1 every o-iteration, 2.3x the VALU floor).
//     Weights staged in LDS, read via wave-uniform ds_read_b128 (broadcast,
//     DS pipe, no dependence on uniform-load scalarization).
//     pack_x vectorized float4 along w.

#define HH 112
#define WW 112
#define CC 128
#define OO 128
#define NN 32
#define HP 114   // padded (halo = zeroed -> corrected via corr table)
#define WP 114
#define W4 28    // 112 / 4

// ---------------- pass 1: pack sign(x) into 128-bit masks per pixel ----------------
// Each thread: one 32-channel word (wd) x 4 consecutive pixels (float4 loads).
__global__ __launch_bounds__(128) void pack_x_kernel(const float* __restrict__ x,
                                                     uint64_t* __restrict__ xb) {
  int t = threadIdx.x;
  int q  = t & 31;   // float4 index along w (0..27 used)
  int wd = t >> 5;   // which 32-channel word (0..3)
  int h = blockIdx.x;
  int n = blockIdx.y;
  if (q >= W4) return;
  const float* xp = x + (((size_t)(n * CC + wd * 32) * HH) + h) * WW + q * 4;
  unsigned int m0 = 0u, m1 = 0u, m2 = 0u, m3 = 0u;
#pragma unroll
  for (int b = 0; b < 32; b++) {
    float4 v = *(const float4*)xp;           // channel wd*32+b, pixels q*4..q*4+3
    m0 |= (v.x > 0.0f) ? (1u << b) : 0u;
    m1 |= (v.y > 0.0f) ? (1u << b) : 0u;
    m2 |= (v.z > 0.0f) ? (1u << b) : 0u;
    m3 |= (v.w > 0.0f) ? (1u << b) : 0u;
    xp += HH * WW;
  }
  // xb viewed as u32 words: word index = pixel*4 + wd  (little-endian u64 pairs)
  unsigned int* xb32 = (unsigned int*)xb;
  size_t pix = ((size_t)n * HP + (h + 1)) * WP + (q * 4 + 1);
  xb32[(pix + 0) * 4 + wd] = m0;
  xb32[(pix + 1) * 4 + wd] = m1;
  xb32[(pix + 2) * 4 + wd] = m2;
  xb32[(pix + 3) * 4 + wd] = m3;
}

// ---------------- pass 0: weight scale + bitmasks + border-correction table --------
__global__ __launch_bounds__(256) void prep_w_kernel(const float* __restrict__ wt,
                                                     uint64_t* __restrict__ wbits,
                                                     float* __restrict__ scale,
                                                     int* __restrict__ corr) {
  int o = blockIdx.x;
  const float* wo = wt + (size_t)o * (CC * 9);
  __shared__ unsigned int bits[9][4];
  __shared__ float red[256];
  int t = threadIdx.x;
  if (t < 36) ((unsigned int*)bits)[t] = 0u;
  __syncthreads();
  float s = 0.0f;
  for (int idx = t; idx < CC * 9; idx += 256) {
    float v = wo[idx];
    s += fabsf(v);
    int ci = idx / 9, tap = idx % 9;      // OIHW: [i][kh][kw], tap = kh*3+kw
    if (v > 0.0f) atomicOr(&bits[tap][ci >> 5], 1u << (ci & 31));
  }
  red[t] = s;
  __syncthreads();
  for (int st = 128; st > 0; st >>= 1) {
    if (t < st) red[t] += red[t + st];
    __syncthreads();
  }
  if (t == 0) {
    scale[o] = red[0] * (1.0f / 1152.0f);
    int c[9];
#pragma unroll
    for (int tap = 0; tap < 9; tap++) {
      uint64_t lo = (uint64_t)bits[tap][0] | ((uint64_t)bits[tap][1] << 32);
      uint64_t hi = (uint64_t)bits[tap][2] | ((uint64_t)bits[tap][3] << 32);
      wbits[o * 18 + tap * 2]     = lo;
      wbits[o * 18 + tap * 2 + 1] = hi;
      c[tap] = 128 - 2 * (__builtin_popcountll(lo) + __builtin_popcountll(hi));
    }
    // 9 border patterns: pat = ph*3+pw, ph/pw: 0=low edge,1=interior,2=high edge.
    for (int ph = 0; ph < 3; ph++)
      for (int pw = 0; pw < 3; pw++) {
        int sum = 0;
        for (int tap = 0; tap < 9; tap++) {
          int kh = tap / 3, kw = tap % 3;
          bool inv = (ph == 0 && kh == 0) || (ph == 2 && kh == 2) ||
                     (pw == 0 && kw == 0) || (pw == 2 && kw == 2);
          if (inv) sum += c[tap];  // spurious term from zeroed halo word
        }
        corr[o * 9 + ph * 3 + pw] = sum;
      }
  }
}

// ---------------- pass 2: XNOR-popcount conv -------------------------------------
// tap-outer / o-inner: each x-word loaded exactly once; pc[32] accumulators live
// in VGPRs (static indices, full unroll). Weights come from LDS via wave-uniform
// broadcast ds_read_b128 (no bank conflicts, no VALU/VMEM slots).
__global__ __launch_bounds__(256, 4) void conv_kernel(const uint64_t* __restrict__ xb,
                                                      const uint64_t* __restrict__ wbits,
                                                      const float* __restrict__ scale,
                                                      const int* __restrict__ corr,
                                                      float* __restrict__ out) {
  __shared__ uint64_t wlds[OO * 18];   // 18432 B
  __shared__ float    slds[OO];        //   512 B
  int t = threadIdx.x;
  {  // stage weights: 1152 x ulonglong2, 256 threads
    ulonglong2* dst = (ulonglong2*)wlds;
    const ulonglong2* src = (const ulonglong2*)wbits;
#pragma unroll
    for (int i = 0; i < 5; i++) {
      int idx = t + i * 256;
      if (idx < OO * 9) dst[idx] = src[idx];
    }
    if (t < OO) slds[t] = scale[t];
  }
  __syncthreads();

  int og = t >> 6;            // wave-uniform by construction
  int wl = t & 63;
  int w = blockIdx.x * 64 + wl;
  int h = blockIdx.y;
  int n = blockIdx.z;
  if (w >= WW) return;
  int ph = (h == 0) ? 0 : ((h == HH - 1) ? 2 : 1);
  int pw = (w == 0) ? 0 : ((w == WW - 1) ? 2 : 1);
  const int* corrp = corr + (og * 32) * 9 + (ph * 3 + pw);

  const uint64_t* xbase = xb + (((size_t)n * HP + h) * WP + w) * 2;  // padded
  const uint64_t* wb = wlds + (size_t)og * 32 * 18;

  int pc[32];
#pragma unroll
  for (int j = 0; j < 32; j++) pc[j] = 0;

#pragma unroll
  for (int tap = 0; tap < 9; tap++) {
    const int dh = tap / 3, dw = tap % 3;
    const ulonglong2 xv = *(const ulonglong2*)(xbase + ((size_t)dh * WP + dw) * 2);
#pragma unroll
    for (int j = 0; j < 32; j++) {
      const ulonglong2 wv = *(const ulonglong2*)(wb + j * 18 + tap * 2);  // ds_read_b128, uniform
      pc[j] += __builtin_popcountll(xv.x ^ wv.x);
      pc[j] += __builtin_popcountll(xv.y ^ wv.y);
    }
  }

  size_t obase = (((size_t)(n * OO + og * 32)) * HH + h) * WW + w;
#pragma unroll
  for (int j = 0; j < 32; j++) {
    int dot = 1152 - 2 * pc[j] - corrp[j * 9];   // halo correction (0 interior)
    out[obase + (size_t)j * (HH * WW)] = slds[og * 32 + j] * (float)dot;
  }
}

extern "C" void kernel_launch(void* const* d_in, const int* in_sizes, int n_in,
                              void* d_out, int out_size, void* d_ws, size_t ws_size,
                              hipStream_t stream) {
  const float* x  = (const float*)d_in[0];
  const float* wt = (const float*)d_in[1];
  float* out = (float*)d_out;

  char* ws = (char*)d_ws;
  size_t xb_elems = (size_t)NN * HP * WP * 2;       // u64 count = 831,744 (6.65 MB)
  uint64_t* xb    = (uint64_t*)ws;
  size_t off = xb_elems * 8;
  uint64_t* wbits = (uint64_t*)(ws + off); off += (size_t)OO * 18 * 8;  // 18 KB
  float* scale    = (float*)(ws + off);    off += (size_t)OO * 4;
  int* corr       = (int*)(ws + off);      off += (size_t)OO * 9 * 4;

  // zero halo (and interior, overwritten by pack) — ws is re-poisoned every call
  hipMemsetAsync(xb, 0, xb_elems * 8, stream);
  hipLaunchKernelGGL(pack_x_kernel, dim3(HH, NN), dim3(128), 0, stream, x, xb);
  hipLaunchKernelGGL(prep_w_kernel, dim3(OO), dim3(256), 0, stream, wt, wbits, scale, corr);
  hipLaunchKernelGGL(conv_kernel, dim3(2, HH, NN), dim3(256), 0, stream,
                     xb, wbits, scale, corr, out);
}